// Round 2
// baseline (759.880 us; speedup 1.0000x reference)
//
#include <hip/hip_runtime.h>

// Fused LSTM: T=2048 steps, B=1024 chains, I=4, H=10, O=4.
// Layout: 6 chains per wave, 10 lanes per chain (lane = one hidden unit).
// Each lane computes gates i,f,g,o for its unit via packed-f16 v_dot2.
// h shared cross-lane via ds_swizzle + ds_bpermute (register-only, no LDS,
// no barriers -> x[t+1] prefetch stays in flight across the whole step).

typedef __fp16 half2_t __attribute__((ext_vector_type(2)));  // matches V2h builtin sigs

#define T_STEPS 2048
#define BATCH   1024
#define HID     10
#define CPW     6   // chains per wave (60 of 64 lanes active)

__device__ __forceinline__ float fdot2(half2_t a, half2_t b, float c) {
    return __builtin_amdgcn_fdot2(a, b, c, false);
}
__device__ __forceinline__ half2_t pkrtz(float a, float b) {
    return __builtin_amdgcn_cvt_pkrtz(a, b);
}
// pre already scaled by -log2(e):  sigma(z) = rcp(1+exp2(pre))
__device__ __forceinline__ float sigm_pre(float pre) {
    return __builtin_amdgcn_rcpf(1.0f + __builtin_amdgcn_exp2f(pre));
}
// pre already scaled by +2*log2(e): tanh(z) = 1 - 2/(e^{2z}+1)
__device__ __forceinline__ float tanh_pre(float pre) {
    return 1.0f - 2.0f * __builtin_amdgcn_rcpf(1.0f + __builtin_amdgcn_exp2f(pre));
}

__global__ __launch_bounds__(64, 1) void lstm_fused(
    const float* __restrict__ x,    const float* __restrict__ h0,
    const float* __restrict__ c0,   const float* __restrict__ W_ih,
    const float* __restrict__ W_hh, const float* __restrict__ b_ih,
    const float* __restrict__ b_hh, const float* __restrict__ W_fc,
    const float* __restrict__ b_fc, float* __restrict__ out)
{
    const int lane = threadIdx.x;          // 0..63
    const int s_raw = lane / HID;          // chain slot 0..6 (6 = idle lanes 60..63)
    const int u     = lane - s_raw * HID;  // hidden unit 0..9
    const bool active = (s_raw < CPW);
    const int s = active ? s_raw : (CPW - 1);        // clamp for index math
    int chain = blockIdx.x * CPW + s;
    const bool valid = active && (chain < BATCH);
    if (chain > BATCH - 1) chain = BATCH - 1;        // clamp for loads

    const float LOG2E = 1.4426950408889634f;

    // ---- prologue: load + prescale + f16-pack weights (per lane: 4 gate rows) ----
    // PyTorch gate-row order: rows [0..9]=i, [10..19]=f, [20..29]=g, [30..39]=o
    half2_t wg[4][7];   // [gate][pair]; pairs 0-1 = W_ih (I=4), 2-6 = W_hh (H=10)
    float   bg[4];
    #pragma unroll
    for (int tau = 0; tau < 4; ++tau) {
        const int r = tau * 10 + u;
        const float sc = (tau == 2) ? (2.0f * LOG2E) : (-LOG2E);
        wg[tau][0] = pkrtz(W_ih[r*4+0]*sc, W_ih[r*4+1]*sc);
        wg[tau][1] = pkrtz(W_ih[r*4+2]*sc, W_ih[r*4+3]*sc);
        #pragma unroll
        for (int p = 0; p < 5; ++p)
            wg[tau][2+p] = pkrtz(W_hh[r*10+2*p]*sc, W_hh[r*10+2*p+1]*sc);
        bg[tau] = (b_ih[r] + b_hh[r]) * sc;
    }
    // output head: lane u<4 owns output row u
    const int orow = u & 3;
    half2_t wfc[5];
    #pragma unroll
    for (int p = 0; p < 5; ++p)
        wfc[p] = pkrtz(W_fc[orow*10+2*p], W_fc[orow*10+2*p+1]);
    const float bfc = b_fc[orow];

    // bpermute byte-indices: pair p lives on lane 10*s + 2*p (even lanes hold (h2p,h2p+1))
    int bidx[5];
    #pragma unroll
    for (int p = 0; p < 5; ++p) bidx[p] = (10*s + 2*p) * 4;

    // ---- initial state ----
    float c = c0[chain*HID + u];
    float h = h0[chain*HID + u];

    half2_t v[7];  // v[0..1] = x pairs (f16), v[2..6] = h pairs (f16)
    {
        // pack (h_u, h_{u^1}) then broadcast the 5 even-lane pairs to all lanes of the chain
        int oth = __builtin_amdgcn_ds_swizzle(__builtin_bit_cast(int, h), 0x041F); // xor 1
        half2_t pk = pkrtz(h, __builtin_bit_cast(float, oth));
        int pki = __builtin_bit_cast(int, pk);
        #pragma unroll
        for (int p = 0; p < 5; ++p)
            v[2+p] = __builtin_bit_cast(half2_t, __builtin_amdgcn_ds_bpermute(bidx[p], pki));
    }
    const float4* x4 = (const float4*)x;       // x[t][b][0..3] as one float4
    float4 xc = x4[chain];                     // x[0][b]
    v[0] = pkrtz(xc.x, xc.y);
    v[1] = pkrtz(xc.z, xc.w);
    float4 xn = x4[BATCH + chain];             // prefetch x[1][b]

    const size_t out_base = (size_t)chain * 4 + orow;
    float* __restrict__ hs_out = out;                                  // [T*B,4]
    float* __restrict__ hT_out = out + (size_t)T_STEPS * BATCH * 4;    // [B,10]
    float* __restrict__ cT_out = hT_out + BATCH * HID;                 // [B,10]

    for (int t = 0; t < T_STEPS; ++t) {
        // ---- gates: 4 parallel dot chains over 7 packed pairs ----
        float pi = bg[0], pf = bg[1], pg = bg[2], po = bg[3];
        #pragma unroll
        for (int p = 0; p < 7; ++p) {
            pi = fdot2(wg[0][p], v[p], pi);
            pf = fdot2(wg[1][p], v[p], pf);
            pg = fdot2(wg[2][p], v[p], pg);
            po = fdot2(wg[3][p], v[p], po);
        }
        const float si = sigm_pre(pi);
        const float sf = sigm_pre(pf);
        const float so = sigm_pre(po);
        const float tg = tanh_pre(pg);
        c = sf * c + si * tg;
        const float tc = tanh_pre(2.0f * LOG2E * c);
        h = so * tc;

        // ---- share new h across the chain's 10 lanes (register-only) ----
        int oth = __builtin_amdgcn_ds_swizzle(__builtin_bit_cast(int, h), 0x041F);
        half2_t pk = pkrtz(h, __builtin_bit_cast(float, oth));
        int pki = __builtin_bit_cast(int, pk);
        #pragma unroll
        for (int p = 0; p < 5; ++p)
            v[2+p] = __builtin_bit_cast(half2_t, __builtin_amdgcn_ds_bpermute(bidx[p], pki));

        // ---- fused output projection: out[t][b][orow], lanes u<4 ----
        float o = bfc;
        #pragma unroll
        for (int p = 0; p < 5; ++p) o = fdot2(wfc[p], v[2+p], o);
        if (valid && u < 4)
            hs_out[(size_t)t * (BATCH*4) + out_base] = o;

        // ---- advance x: consume prefetched x[t+1], issue load of x[t+2] ----
        v[0] = pkrtz(xn.x, xn.y);
        v[1] = pkrtz(xn.z, xn.w);
        const int tn = (t + 2 < T_STEPS) ? (t + 2) : (T_STEPS - 1);
        xn = x4[(size_t)tn * BATCH + chain];
    }

    if (valid) {
        hT_out[chain*HID + u] = h;
        cT_out[chain*HID + u] = c;
    }
}

extern "C" void kernel_launch(void* const* d_in, const int* in_sizes, int n_in,
                              void* d_out, int out_size, void* d_ws, size_t ws_size,
                              hipStream_t stream) {
    const float* x    = (const float*)d_in[0];
    const float* h0   = (const float*)d_in[1];
    const float* c0   = (const float*)d_in[2];
    const float* W_ih = (const float*)d_in[3];
    const float* W_hh = (const float*)d_in[4];
    const float* b_ih = (const float*)d_in[5];
    const float* b_hh = (const float*)d_in[6];
    const float* W_fc = (const float*)d_in[7];
    const float* b_fc = (const float*)d_in[8];
    float* out = (float*)d_out;

    const int nblocks = (BATCH + CPW - 1) / CPW;  // 171
    lstm_fused<<<dim3(nblocks), dim3(64), 0, stream>>>(
        x, h0, c0, W_ih, W_hh, b_ih, b_hh, W_fc, b_fc, out);
}